// Round 4
// baseline (832.809 us; speedup 1.0000x reference)
//
#include <hip/hip_runtime.h>
#include <stdint.h>

// ClusterHead: P = softmax_k( x . c_k - 0.5*||c_k||^2 )   (||x||^2 cancels)
// Split-bf16: x.c = x_hi.c_hi + x_lo.c_hi + x_hi.c_lo.
// R4: LDS cut to 72KB -> 2 blocks/CU (4 waves/SIMD) for cross-block latency
// hiding. 2-deep B ring (prefetch distance 1), reg-staged x (T14), single
// Abuf (A-frags are reg-resident from J0), bias in registers, epilogue
// scratch aliased into Bbuf. All 64 sub-iters uniform (wrapped tail index).

namespace {
constexpr int N_ROWS  = 32768;
constexpr int K_CL    = 1024;
constexpr int D_DIM   = 512;
constexpr int BM      = 64;
constexpr int THREADS = 512;
constexpr int WAVES   = 8;
constexpr int NSLICE  = 16;     // k-slices of 32
}

typedef __bf16 bf16_t;
typedef __bf16 bf16x8 __attribute__((ext_vector_type(8)));
typedef __bf16 bf16x4 __attribute__((ext_vector_type(4)));
typedef float  f32x4  __attribute__((ext_vector_type(4)));

__device__ inline void async_copy16(const void* g, void* l) {
  __builtin_amdgcn_global_load_lds(
      (const __attribute__((address_space(1))) uint32_t*)g,
      (__attribute__((address_space(3))) uint32_t*)l, 16, 0, 0);
}

// ---- prep: bpack sub-images [s][g][col] 16B chunks (k-major, conflict-free)
// sub-image s = 4*t + j : j0/j1 = c_hi cols 0-511 / 512-1023, j2/j3 = c_lo halves.
__global__ __launch_bounds__(64) void prep_kernel(const float* __restrict__ centers,
                                                  bf16_t* __restrict__ bpack,
                                                  float* __restrict__ bias) {
  const int col = blockIdx.x, lane = threadIdx.x;
  const int t = lane >> 2, g = lane & 3;   // lane owns d in [lane*8, lane*8+8)
  const float* src = centers + (size_t)col * D_DIM + lane * 8;
  bf16x8 hi, lo;
  float ssq = 0.f;
  #pragma unroll
  for (int i = 0; i < 8; ++i) {
    float v = src[i];
    ssq += v * v;
    bf16_t h = (bf16_t)v;
    hi[i] = h;
    lo[i] = (bf16_t)(v - (float)h);
  }
  const int jh = col >> 9, c = col & 511;
  *(bf16x8*)(bpack + ((size_t)(4 * t + jh)     * 2048 + g * 512 + c) * 8) = hi;
  *(bf16x8*)(bpack + ((size_t)(4 * t + 2 + jh) * 2048 + g * 512 + c) * 8) = lo;
  for (int off = 32; off; off >>= 1) ssq += __shfl_down(ssq, off, 64);
  if (lane == 0) bias[col] = -0.5f * ssq;
}

// ---- main fused kernel: 64 rows x 1024 cols per block ----
__global__ __launch_bounds__(THREADS, 4) void cluster_kernel(
    const float* __restrict__ x, const bf16_t* __restrict__ bpack,
    const float* __restrict__ bias, float* __restrict__ out) {
  __shared__ bf16_t Bbuf[2][16384];   // 64KB ping-pong
  __shared__ bf16_t Abuf[2][2048];    // 8KB [hi/lo][(gk*64+row)*8]

  const int tid  = threadIdx.x;
  const int wid  = tid >> 6;
  const int lane = tid & 63;
  const int g    = lane >> 4;
  const int l15  = lane & 15;
  const int brow = blockIdx.x * BM;
  const int xrow = tid >> 3, q = tid & 7, gk = q >> 1, qh = q & 1;

  // ---- bias -> registers (drained before the DMA FIFO starts) ----
  float bcol[8];
  #pragma unroll
  for (int cc = 0; cc < 8; ++cc)
    bcol[cc] = bias[(cc >> 2) * 512 + wid * 64 + (cc & 3) * 16 + l15];
  asm volatile("s_waitcnt vmcnt(0)" ::: "memory");

  f32x4 acc[4][8];
  #pragma unroll
  for (int rb = 0; rb < 4; ++rb)
    #pragma unroll
    for (int cc = 0; cc < 8; ++cc) acc[rb][cc] = (f32x4){0.f, 0.f, 0.f, 0.f};

#define STAGE_B(SIDX, BUF)                                                     \
  {                                                                            \
    const char* gs_ = (const char*)bpack + (size_t)(SIDX) * 32768 +            \
                      wid * 4096 + lane * 16;                                  \
    char* ld_ = (char*)&Bbuf[(BUF)][0] + wid * 4096;                           \
    _Pragma("unroll")                                                          \
    for (int i_ = 0; i_ < 4; ++i_)                                             \
      async_copy16(gs_ + i_ * 1024, ld_ + i_ * 1024);                          \
  }
#define CONVERT(XV)                                                            \
  {                                                                            \
    bf16x4 h4_, l4_;                                                           \
    float vv_[4] = {(XV).x, (XV).y, (XV).z, (XV).w};                           \
    _Pragma("unroll")                                                          \
    for (int i_ = 0; i_ < 4; ++i_) {                                           \
      bf16_t h_ = (bf16_t)vv_[i_];                                             \
      h4_[i_] = h_;                                                            \
      l4_[i_] = (bf16_t)(vv_[i_] - (float)h_);                                 \
    }                                                                          \
    *(bf16x4*)&Abuf[0][(gk * 64 + xrow) * 8 + qh * 4] = h4_;                   \
    *(bf16x4*)&Abuf[1][(gk * 64 + xrow) * 8 + qh * 4] = l4_;                   \
  }
#define COMPUTE(J, WITH_LO)                                                    \
    {                                                                          \
      const bf16_t* bb = &Bbuf[(J) & 1][0];                                    \
      _Pragma("unroll")                                                        \
      for (int cb = 0; cb < 4; ++cb) {                                         \
        bf16x8 bfrag = *(const bf16x8*)&bb[(g * 512 + wid * 64 + cb * 16 + l15) * 8]; \
        _Pragma("unroll")                                                      \
        for (int rb = 0; rb < 4; ++rb)                                         \
          acc[rb][((J) & 1) * 4 + cb] = __builtin_amdgcn_mfma_f32_16x16x32_bf16( \
              ahi[rb], bfrag, acc[rb][((J) & 1) * 4 + cb], 0, 0, 0);           \
        if (WITH_LO) {                                                         \
          _Pragma("unroll")                                                    \
          for (int rb = 0; rb < 4; ++rb)                                       \
            acc[rb][((J) & 1) * 4 + cb] = __builtin_amdgcn_mfma_f32_16x16x32_bf16( \
                alo[rb], bfrag, acc[rb][((J) & 1) * 4 + cb], 0, 0, 0);         \
        }                                                                      \
      }                                                                        \
    }
#define FENCE(VMSTR)                                                           \
    asm volatile(VMSTR ::: "memory");                                          \
    __builtin_amdgcn_s_barrier();                                              \
    __builtin_amdgcn_sched_barrier(0);

  // ---- prologue: x(0) -> regs, B(0) -> LDS, convert, drain ----
  const float* xbase = x + (size_t)(brow + xrow) * D_DIM + q * 4;
  {
    float4 xv0 = *(const float4*)(xbase);
    STAGE_B(0, 0);
    CONVERT(xv0);          // compiler inserts the vmcnt wait for xv0
  }
  FENCE("s_waitcnt vmcnt(0) lgkmcnt(0)")

  bf16x8 ahi[4], alo[4];

  // ---- main loop: 16 slices x 4 uniform sub-iters ----
  #pragma unroll 1
  for (int t = 0; t < NSLICE; ++t) {
    const int s0 = 4 * t;
    const int tn = (t + 1) & 15;     // wrapped (slice-0 reload at tail, unused)

    // J0: compute B[0]=hi/h0 (A hi+lo); stage B(s0+1)->B[1]
    STAGE_B(s0 + 1, 1);
    __builtin_amdgcn_sched_barrier(0);
    #pragma unroll
    for (int rb = 0; rb < 4; ++rb) {
      ahi[rb] = *(const bf16x8*)&Abuf[0][(g * 64 + rb * 16 + l15) * 8];
      alo[rb] = *(const bf16x8*)&Abuf[1][(g * 64 + rb * 16 + l15) * 8];
    }
    COMPUTE(0, 1)
    FENCE("s_waitcnt vmcnt(0) lgkmcnt(0)")

    // J1: compute B[1]=hi/h1; stage B(s0+2)->B[0]; issue x(t+1) (after B!)
    STAGE_B(s0 + 2, 0);
    float4 xv = *(const float4*)(xbase + tn * 32);
    __builtin_amdgcn_sched_barrier(0);
    COMPUTE(1, 1)
    FENCE("s_waitcnt vmcnt(1) lgkmcnt(0)")   // B drained, x stays in flight

    // J2: compute B[0]=lo/h0 (A hi only); stage B(s0+3)->B[1]; convert x
    STAGE_B(s0 + 3, 1);
    __builtin_amdgcn_sched_barrier(0);
    CONVERT(xv)            // Abuf safe: frags reg-resident since J0
    COMPUTE(2, 0)
    FENCE("s_waitcnt vmcnt(0) lgkmcnt(0)")

    // J3: compute B[1]=lo/h1; stage B((s0+4)&63)->B[0] (wraps at tail)
    STAGE_B((s0 + 4) & 63, 0);
    __builtin_amdgcn_sched_barrier(0);
    COMPUTE(3, 0)
    FENCE("s_waitcnt vmcnt(0) lgkmcnt(0)")
  }

  __syncthreads();   // full drain; Bbuf reusable as epilogue scratch

  // ---- epilogue: fused softmax over 1024 columns ----
  float* red = (float*)&Bbuf[0][0];      // WAVES*BM floats
  float* fin = red + WAVES * BM;         // BM floats

  float rmax[4][4];
  #pragma unroll
  for (int rb = 0; rb < 4; ++rb) {
    #pragma unroll
    for (int j = 0; j < 4; ++j) {
      float m = -3.0e38f;
      #pragma unroll
      for (int cc = 0; cc < 8; ++cc) {
        float v = acc[rb][cc][j] + bcol[cc];
        acc[rb][cc][j] = v;
        m = fmaxf(m, v);
      }
      m = fmaxf(m, __shfl_xor(m, 1, 64));
      m = fmaxf(m, __shfl_xor(m, 2, 64));
      m = fmaxf(m, __shfl_xor(m, 4, 64));
      m = fmaxf(m, __shfl_xor(m, 8, 64));
      rmax[rb][j] = m;
    }
  }
  if (l15 == 0) {
    #pragma unroll
    for (int rb = 0; rb < 4; ++rb)
      #pragma unroll
      for (int j = 0; j < 4; ++j)
        red[wid * BM + rb * 16 + g * 4 + j] = rmax[rb][j];
  }
  __syncthreads();
  if (tid < BM) {
    float m = red[tid];
    #pragma unroll
    for (int w = 1; w < WAVES; ++w) m = fmaxf(m, red[w * BM + tid]);
    fin[tid] = m;
  }
  __syncthreads();

  #pragma unroll
  for (int rb = 0; rb < 4; ++rb) {
    #pragma unroll
    for (int j = 0; j < 4; ++j) {
      float m = fin[rb * 16 + g * 4 + j];
      float s = 0.f;
      #pragma unroll
      for (int cc = 0; cc < 8; ++cc) {
        float e = __expf(acc[rb][cc][j] - m);
        acc[rb][cc][j] = e;
        s += e;
      }
      s += __shfl_xor(s, 1, 64);
      s += __shfl_xor(s, 2, 64);
      s += __shfl_xor(s, 4, 64);
      s += __shfl_xor(s, 8, 64);
      rmax[rb][j] = s;
    }
  }
  __syncthreads();
  if (l15 == 0) {
    #pragma unroll
    for (int rb = 0; rb < 4; ++rb)
      #pragma unroll
      for (int j = 0; j < 4; ++j)
        red[wid * BM + rb * 16 + g * 4 + j] = rmax[rb][j];
  }
  __syncthreads();
  if (tid < BM) {
    float s = 0.f;
    #pragma unroll
    for (int w = 0; w < WAVES; ++w) s += red[w * BM + tid];
    fin[tid] = 1.0f / s;
  }
  __syncthreads();

  #pragma unroll
  for (int rb = 0; rb < 4; ++rb) {
    #pragma unroll
    for (int j = 0; j < 4; ++j) {
      const int row = rb * 16 + g * 4 + j;
      const float rs = fin[row];
      #pragma unroll
      for (int cc = 0; cc < 8; ++cc) {
        const int col = (cc >> 2) * 512 + wid * 64 + (cc & 3) * 16 + l15;
        out[(size_t)(brow + row) * K_CL + col] = acc[rb][cc][j] * rs;
      }
    }
  }
}

extern "C" void kernel_launch(void* const* d_in, const int* in_sizes, int n_in,
                              void* d_out, int out_size, void* d_ws, size_t ws_size,
                              hipStream_t stream) {
  const float* x       = (const float*)d_in[0];   // [32768, 512] fp32
  const float* centers = (const float*)d_in[1];   // [1024, 512] fp32
  float* out = (float*)d_out;                     // [32768, 1024] fp32

  bf16_t* bpack = (bf16_t*)d_ws;                                 // 64*32KB = 2MB
  float*  bias  = (float*)((char*)d_ws + (size_t)64 * 32768);    // 4KB

  prep_kernel<<<K_CL, 64, 0, stream>>>(centers, bpack, bias);
  cluster_kernel<<<N_ROWS / BM, THREADS, 0, stream>>>(x, bpack, bias, out);
}

// Round 5
// 109.530 us; speedup vs baseline: 7.6035x; 7.6035x over previous
//
#include <hip/hip_runtime.h>
#include <stdint.h>

// ClusterHead: P = softmax_k( x . c_k - 0.5*||c_k||^2 )   (||x||^2 cancels)
// Split-bf16: x.c = x_hi.c_hi + x_lo.c_hi + x_hi.c_lo.
// R5: B goes global->VGPR directly (coalesced 16B/lane fragment loads,
// register double-buffer, distance-1 prefetch) -> NO per-sub-iter barriers,
// NO manual vmcnt. A stays in LDS ping-pong (convert amortized across waves),
// one __syncthreads per k-slice. Register-bound at 2 waves/SIMD (acc=128);
// latency hiding is pure ILP, which the barrier-free structure enables.

namespace {
constexpr int N_ROWS  = 32768;
constexpr int K_CL    = 1024;
constexpr int D_DIM   = 512;
constexpr int BM      = 64;
constexpr int THREADS = 512;
constexpr int WAVES   = 8;
constexpr int NSLICE  = 16;     // k-slices of 32
}

typedef __bf16 bf16_t;
typedef __bf16 bf16x8 __attribute__((ext_vector_type(8)));
typedef __bf16 bf16x4 __attribute__((ext_vector_type(4)));
typedef float  f32x4  __attribute__((ext_vector_type(4)));

// ---- prep: bpack sub-images [s][g][col] 16B chunks (k-major)
// sub-image s = 4*t + j : j0/j1 = c_hi cols 0-511 / 512-1023, j2/j3 = c_lo halves.
__global__ __launch_bounds__(64) void prep_kernel(const float* __restrict__ centers,
                                                  bf16_t* __restrict__ bpack,
                                                  float* __restrict__ bias) {
  const int col = blockIdx.x, lane = threadIdx.x;
  const int t = lane >> 2, g = lane & 3;   // lane owns d in [lane*8, lane*8+8)
  const float* src = centers + (size_t)col * D_DIM + lane * 8;
  bf16x8 hi, lo;
  float ssq = 0.f;
  #pragma unroll
  for (int i = 0; i < 8; ++i) {
    float v = src[i];
    ssq += v * v;
    bf16_t h = (bf16_t)v;
    hi[i] = h;
    lo[i] = (bf16_t)(v - (float)h);
  }
  const int jh = col >> 9, c = col & 511;
  *(bf16x8*)(bpack + ((size_t)(4 * t + jh)     * 2048 + g * 512 + c) * 8) = hi;
  *(bf16x8*)(bpack + ((size_t)(4 * t + 2 + jh) * 2048 + g * 512 + c) * 8) = lo;
  for (int off = 32; off; off >>= 1) ssq += __shfl_down(ssq, off, 64);
  if (lane == 0) bias[col] = -0.5f * ssq;
}

// ---- main fused kernel: 64 rows x 1024 cols per block ----
__global__ __launch_bounds__(THREADS, 2) void cluster_kernel(
    const float* __restrict__ x, const bf16_t* __restrict__ bpack,
    const float* __restrict__ bias, float* __restrict__ out) {
  __shared__ bf16_t Abuf[2][2][2048];   // [slice parity][hi/lo] 16KB
  __shared__ float  red[WAVES * BM];    // 2KB
  __shared__ float  fin[BM];

  const int tid  = threadIdx.x;
  const int wid  = tid >> 6;
  const int lane = tid & 63;
  const int g    = lane >> 4;
  const int l15  = lane & 15;
  const int brow = blockIdx.x * BM;
  const int xrow = tid >> 3, q = tid & 7, gk = q >> 1, qh = q & 1;

  // bias -> registers (plain loads; no vmcnt discipline needed anywhere)
  float bcol[8];
  #pragma unroll
  for (int cc = 0; cc < 8; ++cc)
    bcol[cc] = bias[(cc >> 2) * 512 + wid * 64 + (cc & 3) * 16 + l15];

  f32x4 acc[4][8];
  #pragma unroll
  for (int rb = 0; rb < 4; ++rb)
    #pragma unroll
    for (int cc = 0; cc < 8; ++cc) acc[rb][cc] = (f32x4){0.f, 0.f, 0.f, 0.f};

  // B fragment base: chunk index (g*512 + wid*64 + l15), 16B chunks;
  // sub-image s adds s*2048 chunks; cb adds cb*16 chunks (=256B, imm offset).
  const bf16x8* bbase =
      (const bf16x8*)bpack + ((size_t)g * 512 + wid * 64 + l15);

#define LOADB(S, DST)                                                          \
  {                                                                            \
    const bf16x8* p_ = bbase + (size_t)(S) * 2048;                             \
    _Pragma("unroll")                                                          \
    for (int cb_ = 0; cb_ < 4; ++cb_) (DST)[cb_] = p_[cb_ * 16];               \
  }
#define CONVERT(XV, PAR)                                                       \
  {                                                                            \
    bf16x4 h4_, l4_;                                                           \
    float vv_[4] = {(XV).x, (XV).y, (XV).z, (XV).w};                           \
    _Pragma("unroll")                                                          \
    for (int i_ = 0; i_ < 4; ++i_) {                                           \
      bf16_t h_ = (bf16_t)vv_[i_];                                             \
      h4_[i_] = h_;                                                            \
      l4_[i_] = (bf16_t)(vv_[i_] - (float)h_);                                 \
    }                                                                          \
    *(bf16x4*)&Abuf[(PAR)][0][(gk * 64 + xrow) * 8 + qh * 4] = h4_;            \
    *(bf16x4*)&Abuf[(PAR)][1][(gk * 64 + xrow) * 8 + qh * 4] = l4_;            \
  }
#define COMPUTE(BREG, HALF, WITH_LO)                                           \
  {                                                                            \
    _Pragma("unroll")                                                          \
    for (int cb = 0; cb < 4; ++cb) {                                           \
      _Pragma("unroll")                                                        \
      for (int rb = 0; rb < 4; ++rb)                                           \
        acc[rb][(HALF) * 4 + cb] = __builtin_amdgcn_mfma_f32_16x16x32_bf16(    \
            ahi[rb], (BREG)[cb], acc[rb][(HALF) * 4 + cb], 0, 0, 0);           \
      if (WITH_LO) {                                                           \
        _Pragma("unroll")                                                      \
        for (int rb = 0; rb < 4; ++rb)                                         \
          acc[rb][(HALF) * 4 + cb] = __builtin_amdgcn_mfma_f32_16x16x32_bf16(  \
              alo[rb], (BREG)[cb], acc[rb][(HALF) * 4 + cb], 0, 0, 0);         \
      }                                                                        \
    }                                                                          \
  }

  const float* xbase = x + (size_t)(brow + xrow) * D_DIM + q * 4;
  bf16x8 bcur[4], bnxt[4];

  // ---- prologue: convert x slice 0, prefetch B(0) ----
  {
    float4 xv0 = *(const float4*)xbase;
    CONVERT(xv0, 0)
    LOADB(0, bcur)
  }
  __syncthreads();

  bf16x8 ahi[4], alo[4];

  // ---- main loop: 16 slices x 4 sub-iters, barrier-free inside a slice ----
  #pragma unroll 1
  for (int t = 0; t < NSLICE; ++t) {
    const int s0 = 4 * t;

    // A-fragments for this slice (written during slice t-1, fenced by barrier)
    #pragma unroll
    for (int rb = 0; rb < 4; ++rb) {
      ahi[rb] = *(const bf16x8*)&Abuf[t & 1][0][(g * 64 + rb * 16 + l15) * 8];
      alo[rb] = *(const bf16x8*)&Abuf[t & 1][1][(g * 64 + rb * 16 + l15) * 8];
    }

    // J0: hi/h0 (A hi+lo)
    LOADB(s0 + 1, bnxt)
    COMPUTE(bcur, 0, 1)

    // J1: hi/h1; issue x(t+1)
    LOADB(s0 + 2, bcur)
    float4 xv = *(const float4*)(xbase + ((t + 1) & 15) * 32);
    COMPUTE(bnxt, 1, 1)

    // J2: lo/h0 (A hi only); convert x(t+1) into the other A buffer
    LOADB(s0 + 3, bnxt)
    CONVERT(xv, (t + 1) & 1)
    COMPUTE(bcur, 0, 0)

    // J3: lo/h1; prefetch next slice's first sub-image (wrapped at tail)
    LOADB((s0 + 4) & 63, bcur)
    COMPUTE(bnxt, 1, 0)

    __syncthreads();   // A(t+1) writes visible; bounds wave skew
  }

  // ---- epilogue: fused softmax over 1024 columns ----
  // col(cc) = (cc>>2)*512 + wid*64 + (cc&3)*16 + l15 ; row = rb*16 + g*4 + j
  float rmax[4][4];
  #pragma unroll
  for (int rb = 0; rb < 4; ++rb) {
    #pragma unroll
    for (int j = 0; j < 4; ++j) {
      float m = -3.0e38f;
      #pragma unroll
      for (int cc = 0; cc < 8; ++cc) {
        float v = acc[rb][cc][j] + bcol[cc];
        acc[rb][cc][j] = v;
        m = fmaxf(m, v);
      }
      m = fmaxf(m, __shfl_xor(m, 1, 64));
      m = fmaxf(m, __shfl_xor(m, 2, 64));
      m = fmaxf(m, __shfl_xor(m, 4, 64));
      m = fmaxf(m, __shfl_xor(m, 8, 64));
      rmax[rb][j] = m;
    }
  }
  if (l15 == 0) {
    #pragma unroll
    for (int rb = 0; rb < 4; ++rb)
      #pragma unroll
      for (int j = 0; j < 4; ++j)
        red[wid * BM + rb * 16 + g * 4 + j] = rmax[rb][j];
  }
  __syncthreads();
  if (tid < BM) {
    float m = red[tid];
    #pragma unroll
    for (int w = 1; w < WAVES; ++w) m = fmaxf(m, red[w * BM + tid]);
    fin[tid] = m;
  }
  __syncthreads();

  #pragma unroll
  for (int rb = 0; rb < 4; ++rb) {
    #pragma unroll
    for (int j = 0; j < 4; ++j) {
      float m = fin[rb * 16 + g * 4 + j];
      float s = 0.f;
      #pragma unroll
      for (int cc = 0; cc < 8; ++cc) {
        float e = __expf(acc[rb][cc][j] - m);
        acc[rb][cc][j] = e;
        s += e;
      }
      s += __shfl_xor(s, 1, 64);
      s += __shfl_xor(s, 2, 64);
      s += __shfl_xor(s, 4, 64);
      s += __shfl_xor(s, 8, 64);
      rmax[rb][j] = s;
    }
  }
  __syncthreads();
  if (l15 == 0) {
    #pragma unroll
    for (int rb = 0; rb < 4; ++rb)
      #pragma unroll
      for (int j = 0; j < 4; ++j)
        red[wid * BM + rb * 16 + g * 4 + j] = rmax[rb][j];
  }
  __syncthreads();
  if (tid < BM) {
    float s = 0.f;
    #pragma unroll
    for (int w = 0; w < WAVES; ++w) s += red[w * BM + tid];
    fin[tid] = 1.0f / s;
  }
  __syncthreads();

  #pragma unroll
  for (int rb = 0; rb < 4; ++rb) {
    #pragma unroll
    for (int j = 0; j < 4; ++j) {
      const int row = rb * 16 + g * 4 + j;
      const float rs = fin[row];
      #pragma unroll
      for (int cc = 0; cc < 8; ++cc) {
        const int col = (cc >> 2) * 512 + wid * 64 + (cc & 3) * 16 + l15;
        out[(size_t)(brow + row) * K_CL + col] = acc[rb][cc][j] * rs;
      }
    }
  }
}

extern "C" void kernel_launch(void* const* d_in, const int* in_sizes, int n_in,
                              void* d_out, int out_size, void* d_ws, size_t ws_size,
                              hipStream_t stream) {
  const float* x       = (const float*)d_in[0];   // [32768, 512] fp32
  const float* centers = (const float*)d_in[1];   // [1024, 512] fp32
  float* out = (float*)d_out;                     // [32768, 1024] fp32

  bf16_t* bpack = (bf16_t*)d_ws;                                 // 64*32KB = 2MB
  float*  bias  = (float*)((char*)d_ws + (size_t)64 * 32768);    // 4KB

  prep_kernel<<<K_CL, 64, 0, stream>>>(centers, bpack, bias);
  cluster_kernel<<<N_ROWS / BM, THREADS, 0, stream>>>(x, bpack, bias, out);
}